// Round 1
// 1027.847 us; speedup vs baseline: 1.0685x; 1.0685x over previous
//
#include <hip/hip_runtime.h>
#include <hip/hip_bf16.h>
#include <stdint.h>

// PairEnergies GNN on MI355X — round 7.
// r6 + node FFN routed through the MFMA gk core (was a latency-bound scalar
// GEMV kernel at 62 µs x3: MfmaUtil=0, VALUBusy=23%). Wtnd1/Wtnd2 were
// already transposed into gk's Bt layout; EPI_RELU + EPI_LN epilogues reused;
// float x_mask side-buffer added for EPI_LN's row mask.

typedef __bf16 bf16_t;
typedef __attribute__((ext_vector_type(8))) __bf16 bf16x8;
typedef __attribute__((ext_vector_type(4))) float f32x4;

#define B_    2
#define N_    1024
#define KN    30
#define H_    128
#define L_    3
#define ODIM_ 400
#define NK    (N_ * KN)        // 30720
#define RT    (B_ * N_ * KN)   // 61440
#define BN_   (B_ * N_)        // 2048

#define EPI_PLAIN 0
#define EPI_RELU  1
#define EPI_F32   2
#define EPI_ADDUG 3
#define EPI_LN    4
#define EPI_OUT   5

__device__ __forceinline__ float wred(float v) {
#pragma unroll
  for (int off = 32; off > 0; off >>= 1) v += __shfl_xor(v, off, 64);
  return v;
}

// async global->LDS, 16B per lane; lds base must be wave-uniform.
__device__ __forceinline__ void gld16(const bf16_t* g, bf16_t* l) {
  __builtin_amdgcn_global_load_lds(
      (__attribute__((address_space(1))) void*)(g),
      (__attribute__((address_space(3))) void*)(l), 16, 0, 0);
}

// ================= unified 128x128 MFMA GEMM =================
// C[M,N] = epi(A[M,K] @ Bt[N,ldb]^T(k-window koff) + bias)
// BM=BN=128, BK=64, 4 waves 2x2, wave = 4x4 frags of mfma_f32_16x16x32_bf16.
// LDS layout [row][64k] with granule-XOR swizzle (g' = g ^ (row&7)) so both
// the LDS-DMA staging (linear) and ds_read_b128 frag reads are conflict-free.
__global__ __launch_bounds__(256) void gk(
    const bf16_t* __restrict__ A, int lda,
    const bf16_t* __restrict__ Bt, int ldb, int koff,
    const bf16_t* __restrict__ bias,
    int N, int K, int epi,
    bf16_t* __restrict__ C,
    float* __restrict__ Cf, float* __restrict__ Cf1, int koff1,
    const float* __restrict__ U, const float* __restrict__ G,
    const int* __restrict__ E_idx,
    bf16_t* __restrict__ resid, const float* __restrict__ mvec, int row0g,
    const int* __restrict__ inv, const int* __restrict__ flag,
    void* __restrict__ outp)
{
  __shared__ __align__(16) bf16_t As[128 * 64];
  __shared__ __align__(16) bf16_t Bs[128 * 64];
  __shared__ float lnS[2][128];
  __shared__ float lnS2[2][128];

  float* CfD = Cf;
  if (epi == EPI_F32 && blockIdx.z == 1) { koff = koff1; bias = nullptr; CfD = Cf1; }

  const int tid = threadIdx.x;
  const int w = tid >> 6, l = tid & 63;
  const int wm = w & 1, wn = w >> 1;
  const int row0 = blockIdx.y * 128;
  const int col0 = blockIdx.x * 128;
  const int lr = l >> 3;                 // 0..7
  const int kg8 = ((l & 7) ^ lr) << 3;   // swizzled source granule (elems)

  const bf16_t* ap[4];
  const bf16_t* bp[4];
#pragma unroll
  for (int s = 0; s < 4; ++s) {
    int rA = row0 + w * 32 + s * 8 + lr;
    const bf16_t* abase;
    if (epi == EPI_OUT) {
      int bb = rA / NK;
      abase = A + (size_t)(bb * NK + inv[rA]) * lda;
    } else {
      abase = A + (size_t)rA * lda;
    }
    ap[s] = abase + kg8;
    int rB = col0 + w * 32 + s * 8 + lr;
    if (rB >= N) rB = N - 1;             // clamp; bad cols gated at store
    bp[s] = Bt + (size_t)rB * ldb + koff + kg8;
  }

  const int fm = l & 15, q = l >> 4, fx = fm & 7;
  f32x4 acc[4][4] = {};

  for (int kt = 0; kt < K; kt += 64) {
    __syncthreads();                     // prior frag reads done
#pragma unroll
    for (int s = 0; s < 4; ++s)
      gld16(ap[s] + kt, &As[w * 2048 + s * 512]);
#pragma unroll
    for (int s = 0; s < 4; ++s)
      gld16(bp[s] + kt, &Bs[w * 2048 + s * 512]);
    __syncthreads();                     // DMA drained (compiler vmcnt(0))
#pragma unroll
    for (int h = 0; h < 2; ++h) {
      bf16x8 af[4], bfv[4];
#pragma unroll
      for (int mi = 0; mi < 4; ++mi)
        af[mi] = *reinterpret_cast<const bf16x8*>(
            &As[(wm * 64 + mi * 16 + fm) * 64 + ((((h << 2) | q) ^ fx) << 3)]);
#pragma unroll
      for (int ni = 0; ni < 4; ++ni)
        bfv[ni] = *reinterpret_cast<const bf16x8*>(
            &Bs[(wn * 64 + ni * 16 + fm) * 64 + ((((h << 2) | q) ^ fx) << 3)]);
#pragma unroll
      for (int mi = 0; mi < 4; ++mi)
#pragma unroll
        for (int ni = 0; ni < 4; ++ni)
          acc[mi][ni] = __builtin_amdgcn_mfma_f32_16x16x32_bf16(
              af[mi], bfv[ni], acc[mi][ni], 0, 0, 0);
    }
  }

  // ---- epilogues (C/D layout: row = wm*64+mi*16+q*4+rr, col = wn*64+ni*16+fm)
  if (epi <= EPI_F32) {
#pragma unroll
    for (int ni = 0; ni < 4; ++ni) {
      int col = col0 + wn * 64 + ni * 16 + fm;
      if (col >= N) continue;
      float bv = bias ? (float)bias[col] : 0.f;
#pragma unroll
      for (int mi = 0; mi < 4; ++mi)
#pragma unroll
        for (int rr = 0; rr < 4; ++rr) {
          size_t rg = (size_t)(row0g + row0 + wm * 64 + mi * 16 + q * 4 + rr);
          float v = acc[mi][ni][rr] + bv;
          if (epi == EPI_RELU) v = fmaxf(v, 0.f);
          if (epi == EPI_F32) CfD[rg * N + col] = v;
          else                C[rg * N + col] = (bf16_t)v;
        }
    }
  } else if (epi == EPI_ADDUG) {
#pragma unroll
    for (int mi = 0; mi < 4; ++mi)
#pragma unroll
      for (int rr = 0; rr < 4; ++rr) {
        int rg = row0g + row0 + wm * 64 + mi * 16 + q * 4 + rr;
        const float* Urow = U + (size_t)(rg / KN) * 128;
        const float* Grow = G + (size_t)((rg / NK) * N_ + E_idx[rg]) * 128;
#pragma unroll
        for (int ni = 0; ni < 4; ++ni) {
          int col = wn * 64 + ni * 16 + fm;
          float bv = bias ? (float)bias[col] : 0.f;
          float v = fmaxf(acc[mi][ni][rr] + bv + Urow[col] + Grow[col], 0.f);
          C[(size_t)rg * 128 + col] = (bf16_t)v;
        }
      }
  } else if (epi == EPI_LN) {
    // resid = LN(resid + acc + bias) * (mvec? mvec[rg] : 1);  N must be 128
#pragma unroll
    for (int mi = 0; mi < 4; ++mi)
#pragma unroll
      for (int rr = 0; rr < 4; ++rr) {
        int lrow = wm * 64 + mi * 16 + q * 4 + rr;
        size_t rg = (size_t)(row0g + row0 + lrow);
        float s = 0.f, s2 = 0.f;
#pragma unroll
        for (int ni = 0; ni < 4; ++ni) {
          int col = wn * 64 + ni * 16 + fm;
          float v = acc[mi][ni][rr] + (bias ? (float)bias[col] : 0.f)
                    + (float)resid[rg * 128 + col];
          acc[mi][ni][rr] = v;
          s += v; s2 += v * v;
        }
#pragma unroll
        for (int d = 1; d < 16; d <<= 1) {
          s += __shfl_xor(s, d, 64); s2 += __shfl_xor(s2, d, 64);
        }
        if (fm == (mi * 4 + rr)) { lnS[wn][lrow] = s; lnS2[wn][lrow] = s2; }
      }
    __syncthreads();
#pragma unroll
    for (int mi = 0; mi < 4; ++mi)
#pragma unroll
      for (int rr = 0; rr < 4; ++rr) {
        int lrow = wm * 64 + mi * 16 + q * 4 + rr;
        size_t rg = (size_t)(row0g + row0 + lrow);
        float st = lnS[0][lrow] + lnS[1][lrow];
        float st2 = lnS2[0][lrow] + lnS2[1][lrow];
        float mu = st * (1.f / 128.f);
        float var = fmaxf(st2 * (1.f / 128.f) - mu * mu, 0.f);
        float rstd = rsqrtf(var + 1e-5f);
        float mk = mvec ? mvec[rg] : 1.f;
#pragma unroll
        for (int ni = 0; ni < 4; ++ni) {
          int col = wn * 64 + ni * 16 + fm;
          resid[rg * 128 + col] = (bf16_t)((acc[mi][ni][rr] - mu) * rstd * mk);
        }
      }
  } else {  // EPI_OUT
    const int fl = *flag;
#pragma unroll
    for (int ni = 0; ni < 4; ++ni) {
      int col = col0 + wn * 64 + ni * 16 + fm;
      if (col >= ODIM_) continue;
      float bv = bias ? (float)bias[col] : 0.f;
#pragma unroll
      for (int mi = 0; mi < 4; ++mi)
#pragma unroll
        for (int rr = 0; rr < 4; ++rr) {
          size_t rg = (size_t)(row0 + wm * 64 + mi * 16 + q * 4 + rr);
          float v = acc[mi][ni][rr] + bv;
          size_t idx = rg * ODIM_ + col;
          if (fl) ((bf16_t*)outp)[idx] = (bf16_t)v;
          else    ((float*)outp)[idx]  = v;
        }
    }
  }
}

// ================= dtype sniff =================
__global__ void flag_kernel(const uint32_t* __restrict__ xm_raw,
                            int* __restrict__ flag)
{
  if (threadIdx.x == 0 && blockIdx.x == 0)
    *flag = (xm_raw[0] == 0x3F803F80u) ? 1 : 0;   // 1 = inputs are bf16
}

// ================= fused convert (+ weight transpose) =================
struct ConvSeg { const void* src; void* dst; int n; int K; int N; };
struct ConvArgs { ConvSeg s[29]; };

__global__ __launch_bounds__(256) void conv_kernel(
    ConvArgs a, int nseg, int total8, const int* __restrict__ flag)
{
  int t = blockIdx.x * 256 + threadIdx.x;
  if (t >= total8) return;
  const int fl = *flag;
  int seg = 0, t8 = t;
  while (seg < nseg - 1 && t8 >= (a.s[seg].n >> 3)) { t8 -= a.s[seg].n >> 3; ++seg; }
  const ConvSeg sg = a.s[seg];
  const int e = t8 << 3;
  float vals[8];
  if (fl) {
    union { uint4 v; bf16_t b[8]; } u;
    u.v = *((const uint4*)sg.src + t8);
#pragma unroll
    for (int j = 0; j < 8; ++j) vals[j] = (float)u.b[j];
  } else {
    const float* sp = (const float*)sg.src + e;
#pragma unroll
    for (int j = 0; j < 8; ++j) vals[j] = sp[j];
  }
  if (sg.N == 0) {          // straight copy -> bf16
    union { uint4 v; bf16_t b[8]; } o;
#pragma unroll
    for (int j = 0; j < 8; ++j) o.b[j] = (bf16_t)vals[j];
    *((uint4*)sg.dst + t8) = o.v;
  } else {                  // per-layer transpose [K,N] -> [N,K]
    const int KN_ = sg.K * sg.N;
    const int lay = e / KN_;
    const int rem = e - lay * KN_;
    const int k = rem / sg.N;
    const int n0 = rem - k * sg.N;
    bf16_t* dp = (bf16_t*)sg.dst + (size_t)lay * KN_ + k;
#pragma unroll
    for (int j = 0; j < 8; ++j)
      dp[(size_t)(n0 + j) * sg.K] = (bf16_t)vals[j];
  }
}

// ================= mask_attend (+ float x_mask side copy) =================
__global__ __launch_bounds__(256) void mask_kernel(
    const bf16_t* __restrict__ xm, const int* __restrict__ E_idx,
    float* __restrict__ ma, float* __restrict__ xmf)
{
  int r = blockIdx.x * 256 + threadIdx.x;
  if (r >= RT) return;
  if (r < BN_) xmf[r] = (float)xm[r];
  int b = r / NK;
  int n = (r / KN) % N_;
  ma[r] = (float)xm[b * N_ + E_idx[r]] * (float)xm[b * N_ + n];
}

// ================= node aggregate + LN =================
__global__ __launch_bounds__(128) void node_agg_ln_kernel(
    const bf16_t* __restrict__ m3, const float* __restrict__ ma,
    bf16_t* __restrict__ hV)
{
  int bn = blockIdx.x;
  int c = threadIdx.x;
  const bf16_t* mrow = m3 + (size_t)bn * (KN * H_) + c;
  const float* mar = ma + (size_t)bn * KN;
  float s = 0.f;
#pragma unroll
  for (int k = 0; k < KN; ++k) s = fmaf((float)mrow[(size_t)k * H_], mar[k], s);
  float v = (float)hV[(size_t)bn * H_ + c] + s * (1.0f / 30.0f);

  __shared__ float red[4];
  float ss = wred(v), s2 = wred(v * v);
  int w = c >> 6, lane = c & 63;
  if (lane == 0) { red[w * 2] = ss; red[w * 2 + 1] = s2; }
  __syncthreads();
  float tot = red[0] + red[2], tot2 = red[1] + red[3];
  float mu = tot * (1.f / 128.f);
  float var = fmaxf(tot2 * (1.f / 128.f) - mu * mu, 0.f);
  float rstd = rsqrtf(var + 1e-5f);
  hV[(size_t)bn * H_ + c] = (bf16_t)((v - mu) * rstd);
}

// ================= launch =================
extern "C" void kernel_launch(void* const* d_in, const int* in_sizes, int n_in,
                              void* d_out, int out_size, void* d_ws, size_t ws_size,
                              hipStream_t stream)
{
  const int* E_idx  = (const int*)d_in[2];
  const int* invmap = (const int*)d_in[3];

  // ---- ws (~15.84 MB): read by final out-GEMM while d_out is being written
  char* ws = (char*)d_ws;
  size_t woff = 0;
  auto walloc = [&](size_t bytes) -> char* {
    char* p = ws + woff; woff += (bytes + 255) & ~(size_t)255; return p;
  };
  int*    flag  = (int*)walloc(4);
  bf16_t* WtOut = (bf16_t*)walloc((size_t)51200 * 2);   // [400][128]
  bf16_t* outbc = (bf16_t*)walloc((size_t)400 * 2);
  bf16_t* hE    = (bf16_t*)walloc((size_t)RT * H_ * 2); // 15.73 MB

  // ---- d_out scratch (fully rewritten by the final out-GEMM) ----
  char* ob = (char*)d_out;
  bf16_t* t0 = (bf16_t*)ob;                              // 15.73 MB
  bf16_t* t1 = (bf16_t*)(ob + (size_t)RT * H_ * 2);      // 15.73 MB
  bf16_t* hid = t0;  // edge-FFN hidden [RT/2,512] spans t0+t1 (both dead then)
  size_t ooff = (size_t)RT * H_ * 2 * 2;
  auto oalloc = [&](size_t bytes) -> char* {
    char* p = ob + ooff; ooff += (bytes + 255) & ~(size_t)255; return p;
  };
  bf16_t* WtV  = (bf16_t*)oalloc(16384 * 2);
  bf16_t* bvc  = (bf16_t*)oalloc(128 * 2);
  bf16_t* WtE  = (bf16_t*)oalloc(16384 * 2);
  bf16_t* bec  = (bf16_t*)oalloc(128 * 2);
  bf16_t* Wtn1 = (bf16_t*)oalloc((size_t)147456 * 2);
  bf16_t* nb1c = (bf16_t*)oalloc(384 * 2);
  bf16_t* Wtn2 = (bf16_t*)oalloc((size_t)49152 * 2);
  bf16_t* nb2c = (bf16_t*)oalloc(384 * 2);
  bf16_t* Wtn3 = (bf16_t*)oalloc((size_t)49152 * 2);
  bf16_t* nb3c = (bf16_t*)oalloc(384 * 2);
  bf16_t* Wtnd1 = (bf16_t*)oalloc((size_t)196608 * 2);
  bf16_t* nbd1c = (bf16_t*)oalloc(1536 * 2);
  bf16_t* Wtnd2 = (bf16_t*)oalloc((size_t)196608 * 2);
  bf16_t* nbd2c = (bf16_t*)oalloc(384 * 2);
  bf16_t* Wte1 = (bf16_t*)oalloc((size_t)147456 * 2);
  bf16_t* eb1c = (bf16_t*)oalloc(384 * 2);
  bf16_t* Wte2 = (bf16_t*)oalloc((size_t)49152 * 2);
  bf16_t* eb2c = (bf16_t*)oalloc(384 * 2);
  bf16_t* Wte3 = (bf16_t*)oalloc((size_t)49152 * 2);
  bf16_t* eb3c = (bf16_t*)oalloc(384 * 2);
  bf16_t* Wted1 = (bf16_t*)oalloc((size_t)196608 * 2);
  bf16_t* ebd1c = (bf16_t*)oalloc(1536 * 2);
  bf16_t* Wted2 = (bf16_t*)oalloc((size_t)196608 * 2);
  bf16_t* ebd2c = (bf16_t*)oalloc(384 * 2);
  float*  Ubuf = (float*)oalloc((size_t)BN_ * 128 * 4);  // 1 MB
  float*  Gbuf = (float*)oalloc((size_t)BN_ * 128 * 4);  // 1 MB
  bf16_t* hV   = (bf16_t*)oalloc((size_t)BN_ * 128 * 2);
  float*  ma   = (float*)oalloc((size_t)RT * 4);
  bf16_t* xm   = (bf16_t*)oalloc((size_t)BN_ * 2);
  float*  xmf  = (float*)oalloc((size_t)BN_ * 4);        // float x_mask for EPI_LN
  // ooff tops out ~37 MB < 49.15 MB

  // ---- convert/transpose segment table ----
  ConvArgs ca;
  struct D { int idx; void* dst; int K; int N; };
  const D dl[29] = {
    {0, t1, 0, 0}, {1, t0, 0, 0}, {4, xm, 0, 0},
    {5, WtV, 128, 128}, {6, bvc, 0, 0}, {7, WtE, 128, 128}, {8, bec, 0, 0},
    {9, Wtn1, 384, 128}, {10, nb1c, 0, 0}, {11, Wtn2, 128, 128}, {12, nb2c, 0, 0},
    {13, Wtn3, 128, 128}, {14, nb3c, 0, 0},
    {15, Wtnd1, 128, 512}, {16, nbd1c, 0, 0}, {17, Wtnd2, 512, 128}, {18, nbd2c, 0, 0},
    {19, Wte1, 384, 128}, {20, eb1c, 0, 0}, {21, Wte2, 128, 128}, {22, eb2c, 0, 0},
    {23, Wte3, 128, 128}, {24, eb3c, 0, 0},
    {25, Wted1, 128, 512}, {26, ebd1c, 0, 0}, {27, Wted2, 512, 128}, {28, ebd2c, 0, 0},
    {29, WtOut, 128, 400}, {30, outbc, 0, 0}
  };
  int total8 = 0;
  for (int i = 0; i < 29; ++i) {
    ca.s[i].src = d_in[dl[i].idx];
    ca.s[i].dst = dl[i].dst;
    ca.s[i].n   = in_sizes[dl[i].idx];
    ca.s[i].K   = dl[i].K;
    ca.s[i].N   = dl[i].N;
    total8 += ca.s[i].n >> 3;
  }

  auto g = [&](dim3 grid, const bf16_t* A, int lda, const bf16_t* Bt, int ldb,
               int koff, const bf16_t* bias, int N, int K, int epi,
               bf16_t* C, float* Cf, float* Cf1, int koff1,
               bf16_t* resid, const float* mvec, int row0g) {
    gk<<<grid, 256, 0, stream>>>(A, lda, Bt, ldb, koff, bias, N, K, epi,
        C, Cf, Cf1, koff1, Ubuf, Gbuf, E_idx, resid, mvec, row0g,
        invmap, flag, d_out);
  };
  const float* NOM = nullptr;

  flag_kernel<<<1, 64, 0, stream>>>((const uint32_t*)d_in[4], flag);
  conv_kernel<<<(total8 + 255) / 256, 256, 0, stream>>>(ca, 29, total8, flag);
  mask_kernel<<<RT / 256, 256, 0, stream>>>(xm, E_idx, ma, xmf);

  // embeds
  g(dim3(1, BN_ / 128), t1, 128, WtV, 128, 0, bvc, 128, 128, EPI_PLAIN,
    hV, nullptr, nullptr, 0, nullptr, NOM, 0);
  g(dim3(1, RT / 128), t0, 128, WtE, 128, 0, bec, 128, 128, EPI_PLAIN,
    hE, nullptr, nullptr, 0, nullptr, NOM, 0);

  for (int l = 0; l < L_; ++l) {
    const bf16_t* W1n = Wtn1 + (size_t)l * 49152;
    const bf16_t* W2n = Wtn2 + (size_t)l * 16384;
    const bf16_t* W3n = Wtn3 + (size_t)l * 16384;
    const bf16_t* W1e = Wte1 + (size_t)l * 49152;
    const bf16_t* W2e = Wte2 + (size_t)l * 16384;
    const bf16_t* W3e = Wte3 + (size_t)l * 16384;
    // ---- node update ----
    g(dim3(1, BN_ / 128, 2), hV, 128, W1n, 384, 0, nb1c + l * 128, 128, 128,
      EPI_F32, nullptr, Ubuf, Gbuf, 128, nullptr, NOM, 0);
    g(dim3(1, RT / 128), hE, 128, W1n, 384, 256, nullptr, 128, 128, EPI_ADDUG,
      t0, nullptr, nullptr, 0, nullptr, NOM, 0);
    g(dim3(1, RT / 128), t0, 128, W2n, 128, 0, nb2c + l * 128, 128, 128, EPI_RELU,
      t1, nullptr, nullptr, 0, nullptr, NOM, 0);
    g(dim3(1, RT / 128), t1, 128, W3n, 128, 0, nb3c + l * 128, 128, 128, EPI_PLAIN,
      t0, nullptr, nullptr, 0, nullptr, NOM, 0);
    node_agg_ln_kernel<<<BN_, 128, 0, stream>>>(t0, ma, hV);
    // node FFN via MFMA core: hV[2048,128] @ Wd1^T -> t1[2048,512] (ReLU),
    // then t1 @ Wd2^T -> LN(hV + .) * xm.  (t1 is dead here: m2 consumed.)
    g(dim3(4, BN_ / 128), hV, 128, Wtnd1 + (size_t)l * 65536, 128, 0,
      nbd1c + l * 512, 512, 128, EPI_RELU,
      t1, nullptr, nullptr, 0, nullptr, NOM, 0);
    g(dim3(1, BN_ / 128), t1, 512, Wtnd2 + (size_t)l * 65536, 512, 0,
      nbd2c + l * 128, 128, 512, EPI_LN,
      nullptr, nullptr, nullptr, 0, hV, xmf, 0);
    // ---- edge update ----
    g(dim3(1, BN_ / 128, 2), hV, 128, W1e, 384, 0, eb1c + l * 128, 128, 128,
      EPI_F32, nullptr, Ubuf, Gbuf, 256, nullptr, NOM, 0);
    g(dim3(1, RT / 128), hE, 128, W1e, 384, 128, nullptr, 128, 128, EPI_ADDUG,
      t0, nullptr, nullptr, 0, nullptr, NOM, 0);
    g(dim3(1, RT / 128), t0, 128, W2e, 128, 0, eb2c + l * 128, 128, 128, EPI_RELU,
      t1, nullptr, nullptr, 0, nullptr, NOM, 0);
    g(dim3(1, RT / 128), t1, 128, W3e, 128, 0, eb3c + l * 128, 128, 128, EPI_LN,
      nullptr, nullptr, nullptr, 0, hE, NOM, 0);
    // edge FFN, 2 row-chunks of RT/2; hidden spans t0+t1
    for (int c = 0; c < 2; ++c) {
      int roff = c * (RT / 2);
      g(dim3(4, (RT / 2) / 128), hE + (size_t)roff * 128, 128,
        Wted1 + (size_t)l * 65536, 128, 0, ebd1c + l * 512, 512, 128, EPI_RELU,
        hid, nullptr, nullptr, 0, nullptr, NOM, 0);
      g(dim3(1, (RT / 2) / 128), hid, 512,
        Wted2 + (size_t)l * 65536, 512, 0, ebd2c + l * 128, 128, 512, EPI_LN,
        nullptr, nullptr, nullptr, 0, hE, ma, roff);
    }
  }

  // output head: fused merge_dups gather, dtype-aware store
  g(dim3(4, RT / 128), hE, 128, WtOut, 128, 0, outbc, ODIM_, 128, EPI_OUT,
    nullptr, nullptr, nullptr, 0, nullptr, NOM, 0);
}

// Round 2
// 676.273 us; speedup vs baseline: 1.6239x; 1.5199x over previous
//
#include <hip/hip_runtime.h>
#include <hip/hip_bf16.h>
#include <stdint.h>

// PairEnergies GNN on MI355X — round 8.
// r7 + fused multi-stage chain kernel gc<MODE>: keeps each 128-row tile
// resident in LDS through the whole GEMM chain (node message 3-GEMM; full
// edge update = 3-GEMM + LN + FFN(4x2 GEMM) + LN; node FFN). Eliminates
// ~300 MB/layer of intermediate global round-trips and 15 dispatches.
// gk retained for embeds / U,G (EPI_F32) / output head (EPI_OUT).

typedef __bf16 bf16_t;
typedef __attribute__((ext_vector_type(8))) __bf16 bf16x8;
typedef __attribute__((ext_vector_type(4))) float f32x4;

#define B_    2
#define N_    1024
#define KN    30
#define H_    128
#define L_    3
#define ODIM_ 400
#define NK    (N_ * KN)        // 30720
#define RT    (B_ * N_ * KN)   // 61440
#define BN_   (B_ * N_)        // 2048

#define EPI_PLAIN 0
#define EPI_RELU  1
#define EPI_F32   2
#define EPI_ADDUG 3
#define EPI_LN    4
#define EPI_OUT   5

__device__ __forceinline__ float wred(float v) {
#pragma unroll
  for (int off = 32; off > 0; off >>= 1) v += __shfl_xor(v, off, 64);
  return v;
}

// async global->LDS, 16B per lane; lds base must be wave-uniform.
__device__ __forceinline__ void gld16(const bf16_t* g, bf16_t* l) {
  __builtin_amdgcn_global_load_lds(
      (__attribute__((address_space(1))) void*)(g),
      (__attribute__((address_space(3))) void*)(l), 16, 0, 0);
}

// one BK=64 round of 128x128 MFMA: A-half [128][64] (swizzled) x B-half
// [128][64] (swizzled) -> acc[4][4] per wave (2x2 wave grid).
__device__ __forceinline__ void mm64(const bf16_t* __restrict__ Ah,
                                     const bf16_t* __restrict__ Bh,
                                     int wm, int wn, int fm, int q, int fx,
                                     f32x4 (&acc)[4][4])
{
#pragma unroll
  for (int h = 0; h < 2; ++h) {
    bf16x8 af[4], bfv[4];
#pragma unroll
    for (int mi = 0; mi < 4; ++mi)
      af[mi] = *reinterpret_cast<const bf16x8*>(
          &Ah[(wm * 64 + mi * 16 + fm) * 64 + ((((h << 2) | q) ^ fx) << 3)]);
#pragma unroll
    for (int ni = 0; ni < 4; ++ni)
      bfv[ni] = *reinterpret_cast<const bf16x8*>(
          &Bh[(wn * 64 + ni * 16 + fm) * 64 + ((((h << 2) | q) ^ fx) << 3)]);
#pragma unroll
    for (int mi = 0; mi < 4; ++mi)
#pragma unroll
      for (int ni = 0; ni < 4; ++ni)
        acc[mi][ni] = __builtin_amdgcn_mfma_f32_16x16x32_bf16(
            af[mi], bfv[ni], acc[mi][ni], 0, 0, 0);
  }
}

// ================= fused chain kernel =================
// MODE 0: node message  S1(ADDUG) -> S2(relu) -> S3 -> global out3 (t0)
// MODE 1: edge update   S1(ADDUG) -> S2(relu) -> S3+LN -> X(LDS) ->
//                       4x{ H=relu(X@Wd1c+b) ; accF += H@Wd2c } ->
//                       LN(X+accF+b)*ma -> hE
// MODE 2: node FFN      X = hV tile -> FFN chunks -> LN(X+.)*xm -> hV
struct GCArgs {
  const bf16_t* Ain;
  const bf16_t* W1; int koff1; int ldw1;
  const bf16_t* W2; const bf16_t* b2;
  const bf16_t* W3; const bf16_t* b3;
  const float* U; const float* G; const int* E;
  const bf16_t* resid;      // global resid for S3-LN (MODE 1)
  bf16_t* out3;             // MODE 0 output (t0)
  const bf16_t* Wd1; const bf16_t* bd1;
  const bf16_t* Wd2; const bf16_t* bd2;
  const float* mvec;        // ma (MODE 1) / xmf (MODE 2)
  bf16_t* outF;             // hE (MODE 1) / hV (MODE 2)
};

template<int MODE>
__global__ __launch_bounds__(256, 2) void gc(GCArgs a)
{
  __shared__ __align__(16) bf16_t bufA[2][8192];   // 32 KB
  __shared__ __align__(16) bf16_t bufB[2][8192];   // 32 KB
  __shared__ __align__(16) bf16_t Ws[8192];        // 16 KB (weights / LN scratch)
  float* lnS  = (float*)Ws;          // [2][128], valid only between stages
  float* lnS2 = lnS + 256;

  const int tid = threadIdx.x;
  const int w = tid >> 6, l = tid & 63;
  const int wm = w & 1, wn = w >> 1;
  const int row0 = blockIdx.x * 128;
  const int lr = l >> 3;
  const int kg8 = ((l & 7) ^ lr) << 3;   // swizzled source granule (elems)
  const int fm = l & 15, q = l >> 4, fx = fm & 7;
  const int r4 = w * 32 + lr;            // staging row base (s adds 8)

  // ---- stage activation tile (128 rows x K=128) ----
  {
    bf16_t* dst = (MODE == 2) ? bufB[0] : bufA[0];
    const bf16_t* gb = a.Ain + (size_t)(row0 + r4) * 128 + kg8;
#pragma unroll
    for (int kt = 0; kt < 2; ++kt)
#pragma unroll
      for (int s = 0; s < 4; ++s)
        gld16(gb + (size_t)s * 8 * 128 + kt * 64,
              dst + kt * 8192 + w * 2048 + s * 512);
  }

  // K=128 GEMM stage: SRC (LDS, [2][8192] swizzled) x W^T (global, row-major
  // [N=128 rows][ldw], k-window koff) accumulated into acc.
  auto do_gemm = [&](const bf16_t* SRC, const bf16_t* W, int koff, int ldw,
                     f32x4 (&acc)[4][4]) {
#pragma unroll
    for (int kt = 0; kt < 2; ++kt) {
      __syncthreads();                 // prev Ws/SRC consumers done
      const bf16_t* gb = W + (size_t)r4 * ldw + koff + kt * 64 + kg8;
#pragma unroll
      for (int s = 0; s < 4; ++s)
        gld16(gb + (size_t)s * 8 * ldw, &Ws[w * 2048 + s * 512]);
      __syncthreads();                 // DMA drained (compiler vmcnt(0))
      mm64(SRC + kt * 8192, Ws, wm, wn, fm, q, fx, acc);
    }
  };

  // write acc (post-epilogue) back to an LDS activation buffer (swizzled)
  auto wb = [&](f32x4 (&acc)[4][4], bf16_t* dst) {
#pragma unroll
    for (int mi = 0; mi < 4; ++mi)
#pragma unroll
      for (int rr = 0; rr < 4; ++rr) {
        int row = wm * 64 + mi * 16 + q * 4 + rr;
#pragma unroll
        for (int ni = 0; ni < 4; ++ni) {
          int cl = ni * 16 + fm;       // col within this wave's half
          dst[wn * 8192 + row * 64 +
              ((((cl >> 3) ^ (row & 7)) << 3) | (cl & 7))] =
              (bf16_t)acc[mi][ni][rr];
        }
      }
  };

  if constexpr (MODE <= 1) {
    // ---- S1: m1 = relu(A @ W1(koff) + U + G) -> bufB ----
    f32x4 acc1[4][4] = {};
    do_gemm(bufA[0], a.W1, a.koff1, a.ldw1, acc1);
#pragma unroll
    for (int mi = 0; mi < 4; ++mi)
#pragma unroll
      for (int rr = 0; rr < 4; ++rr) {
        int rg = row0 + wm * 64 + mi * 16 + q * 4 + rr;
        const float* Ur = a.U + (size_t)(rg / KN) * 128;
        const float* Gr = a.G + (size_t)((rg / NK) * N_ + a.E[rg]) * 128;
#pragma unroll
        for (int ni = 0; ni < 4; ++ni) {
          int col = wn * 64 + ni * 16 + fm;
          acc1[mi][ni][rr] = fmaxf(acc1[mi][ni][rr] + Ur[col] + Gr[col], 0.f);
        }
      }
    wb(acc1, bufB[0]);

    // ---- S2: m2 = relu(m1 @ W2 + b2) -> bufA ----
    f32x4 acc2[4][4] = {};
    do_gemm(bufB[0], a.W2, 0, 128, acc2);
#pragma unroll
    for (int mi = 0; mi < 4; ++mi)
#pragma unroll
      for (int rr = 0; rr < 4; ++rr)
#pragma unroll
        for (int ni = 0; ni < 4; ++ni) {
          int col = wn * 64 + ni * 16 + fm;
          acc2[mi][ni][rr] = fmaxf(acc2[mi][ni][rr] + (float)a.b2[col], 0.f);
        }
    wb(acc2, bufA[0]);

    // ---- S3: m3 = m2 @ W3 + b3 ----
    f32x4 acc3[4][4] = {};
    do_gemm(bufA[0], a.W3, 0, 128, acc3);

    if constexpr (MODE == 0) {
      // store to t0 for node aggregation
#pragma unroll
      for (int mi = 0; mi < 4; ++mi)
#pragma unroll
        for (int rr = 0; rr < 4; ++rr) {
          size_t rg = (size_t)(row0 + wm * 64 + mi * 16 + q * 4 + rr);
#pragma unroll
          for (int ni = 0; ni < 4; ++ni) {
            int col = wn * 64 + ni * 16 + fm;
            a.out3[rg * 128 + col] =
                (bf16_t)(acc3[mi][ni][rr] + (float)a.b3[col]);
          }
        }
      return;
    } else {
      // S3-LN: X = LN(hE + m3 + b3) -> bufB (LDS only)
      __syncthreads();   // all mm64 Ws reads done; Ws reusable as lnS
#pragma unroll
      for (int mi = 0; mi < 4; ++mi)
#pragma unroll
        for (int rr = 0; rr < 4; ++rr) {
          int lrow = wm * 64 + mi * 16 + q * 4 + rr;
          size_t rg = (size_t)(row0 + lrow);
          float s = 0.f, s2 = 0.f;
#pragma unroll
          for (int ni = 0; ni < 4; ++ni) {
            int col = wn * 64 + ni * 16 + fm;
            float v = acc3[mi][ni][rr] + (float)a.b3[col]
                      + (float)a.resid[rg * 128 + col];
            acc3[mi][ni][rr] = v;
            s += v; s2 += v * v;
          }
#pragma unroll
          for (int d = 1; d < 16; d <<= 1) {
            s += __shfl_xor(s, d, 64); s2 += __shfl_xor(s2, d, 64);
          }
          if (fm == (mi * 4 + rr)) { lnS[wn * 128 + lrow] = s;
                                     lnS2[wn * 128 + lrow] = s2; }
        }
      __syncthreads();
#pragma unroll
      for (int mi = 0; mi < 4; ++mi)
#pragma unroll
        for (int rr = 0; rr < 4; ++rr) {
          int lrow = wm * 64 + mi * 16 + q * 4 + rr;
          float st = lnS[lrow] + lnS[128 + lrow];
          float st2 = lnS2[lrow] + lnS2[128 + lrow];
          float mu = st * (1.f / 128.f);
          float var = fmaxf(st2 * (1.f / 128.f) - mu * mu, 0.f);
          float rstd = rsqrtf(var + 1e-5f);
#pragma unroll
          for (int ni = 0; ni < 4; ++ni) {
            int cl = ni * 16 + fm;
            bufB[wn][lrow * 64 +
                ((((cl >> 3) ^ (lrow & 7)) << 3) | (cl & 7))] =
                (bf16_t)((acc3[mi][ni][rr] - mu) * rstd);
          }
        }
    }
  }

  // ---- FFN: accF = sum_c relu(X @ Wd1_c + bd1_c) @ Wd2_c ; X in bufB ----
  {
    f32x4 accF[4][4] = {};
#pragma unroll 1
    for (int c = 0; c < 4; ++c) {
      f32x4 accH[4][4] = {};
      do_gemm(bufB[0], a.Wd1 + (size_t)c * 128 * 128, 0, 128, accH);
#pragma unroll
      for (int mi = 0; mi < 4; ++mi)
#pragma unroll
        for (int rr = 0; rr < 4; ++rr)
#pragma unroll
          for (int ni = 0; ni < 4; ++ni) {
            int col = wn * 64 + ni * 16 + fm;
            accH[mi][ni][rr] =
                fmaxf(accH[mi][ni][rr] + (float)a.bd1[c * 128 + col], 0.f);
          }
      wb(accH, bufA[0]);
      do_gemm(bufA[0], a.Wd2, c * 128, 512, accF);
    }

    // final LN: out = LN(X + accF + bd2) * mvec
    __syncthreads();   // Ws -> lnS reuse safe
#pragma unroll
    for (int mi = 0; mi < 4; ++mi)
#pragma unroll
      for (int rr = 0; rr < 4; ++rr) {
        int lrow = wm * 64 + mi * 16 + q * 4 + rr;
        float s = 0.f, s2 = 0.f;
#pragma unroll
        for (int ni = 0; ni < 4; ++ni) {
          int cl = ni * 16 + fm;
          float xv = (float)bufB[wn][lrow * 64 +
              ((((cl >> 3) ^ (lrow & 7)) << 3) | (cl & 7))];
          float v = accF[mi][ni][rr] + (float)a.bd2[wn * 64 + cl] + xv;
          accF[mi][ni][rr] = v;
          s += v; s2 += v * v;
        }
#pragma unroll
        for (int d = 1; d < 16; d <<= 1) {
          s += __shfl_xor(s, d, 64); s2 += __shfl_xor(s2, d, 64);
        }
        if (fm == (mi * 4 + rr)) { lnS[wn * 128 + lrow] = s;
                                   lnS2[wn * 128 + lrow] = s2; }
      }
    __syncthreads();
#pragma unroll
    for (int mi = 0; mi < 4; ++mi)
#pragma unroll
      for (int rr = 0; rr < 4; ++rr) {
        int lrow = wm * 64 + mi * 16 + q * 4 + rr;
        size_t rg = (size_t)(row0 + lrow);
        float st = lnS[lrow] + lnS[128 + lrow];
        float st2 = lnS2[lrow] + lnS2[128 + lrow];
        float mu = st * (1.f / 128.f);
        float var = fmaxf(st2 * (1.f / 128.f) - mu * mu, 0.f);
        float rstd = rsqrtf(var + 1e-5f);
        float mk = a.mvec[rg];
#pragma unroll
        for (int ni = 0; ni < 4; ++ni) {
          int col = wn * 64 + ni * 16 + fm;
          a.outF[rg * 128 + col] =
              (bf16_t)((accF[mi][ni][rr] - mu) * rstd * mk);
        }
      }
  }
}

// ================= unified 128x128 MFMA GEMM (embeds / U,G / out head) ====
__global__ __launch_bounds__(256) void gk(
    const bf16_t* __restrict__ A, int lda,
    const bf16_t* __restrict__ Bt, int ldb, int koff,
    const bf16_t* __restrict__ bias,
    int N, int K, int epi,
    bf16_t* __restrict__ C,
    float* __restrict__ Cf, float* __restrict__ Cf1, int koff1,
    const float* __restrict__ U, const float* __restrict__ G,
    const int* __restrict__ E_idx,
    bf16_t* __restrict__ resid, const float* __restrict__ mvec, int row0g,
    const int* __restrict__ inv, const int* __restrict__ flag,
    void* __restrict__ outp)
{
  __shared__ __align__(16) bf16_t As[128 * 64];
  __shared__ __align__(16) bf16_t Bs[128 * 64];
  __shared__ float lnS[2][128];
  __shared__ float lnS2[2][128];

  float* CfD = Cf;
  if (epi == EPI_F32 && blockIdx.z == 1) { koff = koff1; bias = nullptr; CfD = Cf1; }

  const int tid = threadIdx.x;
  const int w = tid >> 6, l = tid & 63;
  const int wm = w & 1, wn = w >> 1;
  const int row0 = blockIdx.y * 128;
  const int col0 = blockIdx.x * 128;
  const int lr = l >> 3;                 // 0..7
  const int kg8 = ((l & 7) ^ lr) << 3;   // swizzled source granule (elems)

  const bf16_t* ap[4];
  const bf16_t* bp[4];
#pragma unroll
  for (int s = 0; s < 4; ++s) {
    int rA = row0 + w * 32 + s * 8 + lr;
    const bf16_t* abase;
    if (epi == EPI_OUT) {
      int bb = rA / NK;
      abase = A + (size_t)(bb * NK + inv[rA]) * lda;
    } else {
      abase = A + (size_t)rA * lda;
    }
    ap[s] = abase + kg8;
    int rB = col0 + w * 32 + s * 8 + lr;
    if (rB >= N) rB = N - 1;             // clamp; bad cols gated at store
    bp[s] = Bt + (size_t)rB * ldb + koff + kg8;
  }

  const int fm = l & 15, q = l >> 4, fx = fm & 7;
  f32x4 acc[4][4] = {};

  for (int kt = 0; kt < K; kt += 64) {
    __syncthreads();                     // prior frag reads done
#pragma unroll
    for (int s = 0; s < 4; ++s)
      gld16(ap[s] + kt, &As[w * 2048 + s * 512]);
#pragma unroll
    for (int s = 0; s < 4; ++s)
      gld16(bp[s] + kt, &Bs[w * 2048 + s * 512]);
    __syncthreads();                     // DMA drained (compiler vmcnt(0))
#pragma unroll
    for (int h = 0; h < 2; ++h) {
      bf16x8 af[4], bfv[4];
#pragma unroll
      for (int mi = 0; mi < 4; ++mi)
        af[mi] = *reinterpret_cast<const bf16x8*>(
            &As[(wm * 64 + mi * 16 + fm) * 64 + ((((h << 2) | q) ^ fx) << 3)]);
#pragma unroll
      for (int ni = 0; ni < 4; ++ni)
        bfv[ni] = *reinterpret_cast<const bf16x8*>(
            &Bs[(wn * 64 + ni * 16 + fm) * 64 + ((((h << 2) | q) ^ fx) << 3)]);
#pragma unroll
      for (int mi = 0; mi < 4; ++mi)
#pragma unroll
        for (int ni = 0; ni < 4; ++ni)
          acc[mi][ni] = __builtin_amdgcn_mfma_f32_16x16x32_bf16(
              af[mi], bfv[ni], acc[mi][ni], 0, 0, 0);
    }
  }

  // ---- epilogues (C/D layout: row = wm*64+mi*16+q*4+rr, col = wn*64+ni*16+fm)
  if (epi <= EPI_F32) {
#pragma unroll
    for (int ni = 0; ni < 4; ++ni) {
      int col = col0 + wn * 64 + ni * 16 + fm;
      if (col >= N) continue;
      float bv = bias ? (float)bias[col] : 0.f;
#pragma unroll
      for (int mi = 0; mi < 4; ++mi)
#pragma unroll
        for (int rr = 0; rr < 4; ++rr) {
          size_t rg = (size_t)(row0g + row0 + wm * 64 + mi * 16 + q * 4 + rr);
          float v = acc[mi][ni][rr] + bv;
          if (epi == EPI_RELU) v = fmaxf(v, 0.f);
          if (epi == EPI_F32) CfD[rg * N + col] = v;
          else                C[rg * N + col] = (bf16_t)v;
        }
    }
  } else if (epi == EPI_LN) {
    // resid = LN(resid + acc + bias) * (mvec? mvec[rg] : 1);  N must be 128
#pragma unroll
    for (int mi = 0; mi < 4; ++mi)
#pragma unroll
      for (int rr = 0; rr < 4; ++rr) {
        int lrow = wm * 64 + mi * 16 + q * 4 + rr;
        size_t rg = (size_t)(row0g + row0 + lrow);
        float s = 0.f, s2 = 0.f;
#pragma unroll
        for (int ni = 0; ni < 4; ++ni) {
          int col = wn * 64 + ni * 16 + fm;
          float v = acc[mi][ni][rr] + (bias ? (float)bias[col] : 0.f)
                    + (float)resid[rg * 128 + col];
          acc[mi][ni][rr] = v;
          s += v; s2 += v * v;
        }
#pragma unroll
        for (int d = 1; d < 16; d <<= 1) {
          s += __shfl_xor(s, d, 64); s2 += __shfl_xor(s2, d, 64);
        }
        if (fm == (mi * 4 + rr)) { lnS[wn][lrow] = s; lnS2[wn][lrow] = s2; }
      }
    __syncthreads();
#pragma unroll
    for (int mi = 0; mi < 4; ++mi)
#pragma unroll
      for (int rr = 0; rr < 4; ++rr) {
        int lrow = wm * 64 + mi * 16 + q * 4 + rr;
        size_t rg = (size_t)(row0g + row0 + lrow);
        float st = lnS[0][lrow] + lnS[1][lrow];
        float st2 = lnS2[0][lrow] + lnS2[1][lrow];
        float mu = st * (1.f / 128.f);
        float var = fmaxf(st2 * (1.f / 128.f) - mu * mu, 0.f);
        float rstd = rsqrtf(var + 1e-5f);
        float mk = mvec ? mvec[rg] : 1.f;
#pragma unroll
        for (int ni = 0; ni < 4; ++ni) {
          int col = wn * 64 + ni * 16 + fm;
          resid[rg * 128 + col] = (bf16_t)((acc[mi][ni][rr] - mu) * rstd * mk);
        }
      }
  } else if (epi == EPI_OUT) {
    const int fl = *flag;
#pragma unroll
    for (int ni = 0; ni < 4; ++ni) {
      int col = col0 + wn * 64 + ni * 16 + fm;
      if (col >= ODIM_) continue;
      float bv = bias ? (float)bias[col] : 0.f;
#pragma unroll
      for (int mi = 0; mi < 4; ++mi)
#pragma unroll
        for (int rr = 0; rr < 4; ++rr) {
          size_t rg = (size_t)(row0 + wm * 64 + mi * 16 + q * 4 + rr);
          float v = acc[mi][ni][rr] + bv;
          size_t idx = rg * ODIM_ + col;
          if (fl) ((bf16_t*)outp)[idx] = (bf16_t)v;
          else    ((float*)outp)[idx]  = v;
        }
    }
  }
}

// ================= dtype sniff =================
__global__ void flag_kernel(const uint32_t* __restrict__ xm_raw,
                            int* __restrict__ flag)
{
  if (threadIdx.x == 0 && blockIdx.x == 0)
    *flag = (xm_raw[0] == 0x3F803F80u) ? 1 : 0;   // 1 = inputs are bf16
}

// ================= fused convert (+ weight transpose) =================
struct ConvSeg { const void* src; void* dst; int n; int K; int N; };
struct ConvArgs { ConvSeg s[29]; };

__global__ __launch_bounds__(256) void conv_kernel(
    ConvArgs a, int nseg, int total8, const int* __restrict__ flag)
{
  int t = blockIdx.x * 256 + threadIdx.x;
  if (t >= total8) return;
  const int fl = *flag;
  int seg = 0, t8 = t;
  while (seg < nseg - 1 && t8 >= (a.s[seg].n >> 3)) { t8 -= a.s[seg].n >> 3; ++seg; }
  const ConvSeg sg = a.s[seg];
  const int e = t8 << 3;
  float vals[8];
  if (fl) {
    union { uint4 v; bf16_t b[8]; } u;
    u.v = *((const uint4*)sg.src + t8);
#pragma unroll
    for (int j = 0; j < 8; ++j) vals[j] = (float)u.b[j];
  } else {
    const float* sp = (const float*)sg.src + e;
#pragma unroll
    for (int j = 0; j < 8; ++j) vals[j] = sp[j];
  }
  if (sg.N == 0) {          // straight copy -> bf16
    union { uint4 v; bf16_t b[8]; } o;
#pragma unroll
    for (int j = 0; j < 8; ++j) o.b[j] = (bf16_t)vals[j];
    *((uint4*)sg.dst + t8) = o.v;
  } else {                  // per-layer transpose [K,N] -> [N,K]
    const int KN_ = sg.K * sg.N;
    const int lay = e / KN_;
    const int rem = e - lay * KN_;
    const int k = rem / sg.N;
    const int n0 = rem - k * sg.N;
    bf16_t* dp = (bf16_t*)sg.dst + (size_t)lay * KN_ + k;
#pragma unroll
    for (int j = 0; j < 8; ++j)
      dp[(size_t)(n0 + j) * sg.K] = (bf16_t)vals[j];
  }
}

// ================= mask_attend (+ float x_mask side copy) =================
__global__ __launch_bounds__(256) void mask_kernel(
    const bf16_t* __restrict__ xm, const int* __restrict__ E_idx,
    float* __restrict__ ma, float* __restrict__ xmf)
{
  int r = blockIdx.x * 256 + threadIdx.x;
  if (r >= RT) return;
  if (r < BN_) xmf[r] = (float)xm[r];
  int b = r / NK;
  int n = (r / KN) % N_;
  ma[r] = (float)xm[b * N_ + E_idx[r]] * (float)xm[b * N_ + n];
}

// ================= node aggregate + LN =================
__global__ __launch_bounds__(128) void node_agg_ln_kernel(
    const bf16_t* __restrict__ m3, const float* __restrict__ ma,
    bf16_t* __restrict__ hV)
{
  int bn = blockIdx.x;
  int c = threadIdx.x;
  const bf16_t* mrow = m3 + (size_t)bn * (KN * H_) + c;
  const float* mar = ma + (size_t)bn * KN;
  float s = 0.f;
#pragma unroll
  for (int k = 0; k < KN; ++k) s = fmaf((float)mrow[(size_t)k * H_], mar[k], s);
  float v = (float)hV[(size_t)bn * H_ + c] + s * (1.0f / 30.0f);

  __shared__ float red[4];
  float ss = wred(v), s2 = wred(v * v);
  int w = c >> 6, lane = c & 63;
  if (lane == 0) { red[w * 2] = ss; red[w * 2 + 1] = s2; }
  __syncthreads();
  float tot = red[0] + red[2], tot2 = red[1] + red[3];
  float mu = tot * (1.f / 128.f);
  float var = fmaxf(tot2 * (1.f / 128.f) - mu * mu, 0.f);
  float rstd = rsqrtf(var + 1e-5f);
  hV[(size_t)bn * H_ + c] = (bf16_t)((v - mu) * rstd);
}

// ================= launch =================
extern "C" void kernel_launch(void* const* d_in, const int* in_sizes, int n_in,
                              void* d_out, int out_size, void* d_ws, size_t ws_size,
                              hipStream_t stream)
{
  const int* E_idx  = (const int*)d_in[2];
  const int* invmap = (const int*)d_in[3];

  // ---- ws (~15.84 MB): read by final out-GEMM while d_out is being written
  char* ws = (char*)d_ws;
  size_t woff = 0;
  auto walloc = [&](size_t bytes) -> char* {
    char* p = ws + woff; woff += (bytes + 255) & ~(size_t)255; return p;
  };
  int*    flag  = (int*)walloc(4);
  bf16_t* WtOut = (bf16_t*)walloc((size_t)51200 * 2);   // [400][128]
  bf16_t* outbc = (bf16_t*)walloc((size_t)400 * 2);
  bf16_t* hE    = (bf16_t*)walloc((size_t)RT * H_ * 2); // 15.73 MB

  // ---- d_out scratch (fully rewritten by the final out-GEMM) ----
  char* ob = (char*)d_out;
  bf16_t* t0 = (bf16_t*)ob;                              // 15.73 MB
  bf16_t* t1 = (bf16_t*)(ob + (size_t)RT * H_ * 2);      // 15.73 MB
  size_t ooff = (size_t)RT * H_ * 2 * 2;
  auto oalloc = [&](size_t bytes) -> char* {
    char* p = ob + ooff; ooff += (bytes + 255) & ~(size_t)255; return p;
  };
  bf16_t* WtV  = (bf16_t*)oalloc(16384 * 2);
  bf16_t* bvc  = (bf16_t*)oalloc(128 * 2);
  bf16_t* WtE  = (bf16_t*)oalloc(16384 * 2);
  bf16_t* bec  = (bf16_t*)oalloc(128 * 2);
  bf16_t* Wtn1 = (bf16_t*)oalloc((size_t)147456 * 2);
  bf16_t* nb1c = (bf16_t*)oalloc(384 * 2);
  bf16_t* Wtn2 = (bf16_t*)oalloc((size_t)49152 * 2);
  bf16_t* nb2c = (bf16_t*)oalloc(384 * 2);
  bf16_t* Wtn3 = (bf16_t*)oalloc((size_t)49152 * 2);
  bf16_t* nb3c = (bf16_t*)oalloc(384 * 2);
  bf16_t* Wtnd1 = (bf16_t*)oalloc((size_t)196608 * 2);
  bf16_t* nbd1c = (bf16_t*)oalloc(1536 * 2);
  bf16_t* Wtnd2 = (bf16_t*)oalloc((size_t)196608 * 2);
  bf16_t* nbd2c = (bf16_t*)oalloc(384 * 2);
  bf16_t* Wte1 = (bf16_t*)oalloc((size_t)147456 * 2);
  bf16_t* eb1c = (bf16_t*)oalloc(384 * 2);
  bf16_t* Wte2 = (bf16_t*)oalloc((size_t)49152 * 2);
  bf16_t* eb2c = (bf16_t*)oalloc(384 * 2);
  bf16_t* Wte3 = (bf16_t*)oalloc((size_t)49152 * 2);
  bf16_t* eb3c = (bf16_t*)oalloc(384 * 2);
  bf16_t* Wted1 = (bf16_t*)oalloc((size_t)196608 * 2);
  bf16_t* ebd1c = (bf16_t*)oalloc(1536 * 2);
  bf16_t* Wted2 = (bf16_t*)oalloc((size_t)196608 * 2);
  bf16_t* ebd2c = (bf16_t*)oalloc(384 * 2);
  float*  Ubuf = (float*)oalloc((size_t)BN_ * 128 * 4);  // 1 MB
  float*  Gbuf = (float*)oalloc((size_t)BN_ * 128 * 4);  // 1 MB
  bf16_t* hV   = (bf16_t*)oalloc((size_t)BN_ * 128 * 2);
  float*  ma   = (float*)oalloc((size_t)RT * 4);
  bf16_t* xm   = (bf16_t*)oalloc((size_t)BN_ * 2);
  float*  xmf  = (float*)oalloc((size_t)BN_ * 4);        // float x_mask
  // ooff tops out ~37 MB < 49.15 MB

  // ---- convert/transpose segment table ----
  ConvArgs ca;
  struct D { int idx; void* dst; int K; int N; };
  const D dl[29] = {
    {0, t1, 0, 0}, {1, t0, 0, 0}, {4, xm, 0, 0},
    {5, WtV, 128, 128}, {6, bvc, 0, 0}, {7, WtE, 128, 128}, {8, bec, 0, 0},
    {9, Wtn1, 384, 128}, {10, nb1c, 0, 0}, {11, Wtn2, 128, 128}, {12, nb2c, 0, 0},
    {13, Wtn3, 128, 128}, {14, nb3c, 0, 0},
    {15, Wtnd1, 128, 512}, {16, nbd1c, 0, 0}, {17, Wtnd2, 512, 128}, {18, nbd2c, 0, 0},
    {19, Wte1, 384, 128}, {20, eb1c, 0, 0}, {21, Wte2, 128, 128}, {22, eb2c, 0, 0},
    {23, Wte3, 128, 128}, {24, eb3c, 0, 0},
    {25, Wted1, 128, 512}, {26, ebd1c, 0, 0}, {27, Wted2, 512, 128}, {28, ebd2c, 0, 0},
    {29, WtOut, 128, 400}, {30, outbc, 0, 0}
  };
  int total8 = 0;
  for (int i = 0; i < 29; ++i) {
    ca.s[i].src = d_in[dl[i].idx];
    ca.s[i].dst = dl[i].dst;
    ca.s[i].n   = in_sizes[dl[i].idx];
    ca.s[i].K   = dl[i].K;
    ca.s[i].N   = dl[i].N;
    total8 += ca.s[i].n >> 3;
  }

  auto g = [&](dim3 grid, const bf16_t* A, int lda, const bf16_t* Bt, int ldb,
               int koff, const bf16_t* bias, int N, int K, int epi,
               bf16_t* C, float* Cf, float* Cf1, int koff1,
               bf16_t* resid, const float* mvec, int row0g) {
    gk<<<grid, 256, 0, stream>>>(A, lda, Bt, ldb, koff, bias, N, K, epi,
        C, Cf, Cf1, koff1, Ubuf, Gbuf, E_idx, resid, mvec, row0g,
        invmap, flag, d_out);
  };
  const float* NOM = nullptr;

  flag_kernel<<<1, 64, 0, stream>>>((const uint32_t*)d_in[4], flag);
  conv_kernel<<<(total8 + 255) / 256, 256, 0, stream>>>(ca, 29, total8, flag);
  mask_kernel<<<RT / 256, 256, 0, stream>>>(xm, E_idx, ma, xmf);

  // embeds
  g(dim3(1, BN_ / 128), t1, 128, WtV, 128, 0, bvc, 128, 128, EPI_PLAIN,
    hV, nullptr, nullptr, 0, nullptr, NOM, 0);
  g(dim3(1, RT / 128), t0, 128, WtE, 128, 0, bec, 128, 128, EPI_PLAIN,
    hE, nullptr, nullptr, 0, nullptr, NOM, 0);

  for (int l = 0; l < L_; ++l) {
    // ---- node update ----
    g(dim3(1, BN_ / 128, 2), hV, 128, Wtn1 + (size_t)l * 49152, 384, 0,
      nb1c + l * 128, 128, 128, EPI_F32,
      nullptr, Ubuf, Gbuf, 128, nullptr, NOM, 0);
    {
      GCArgs na{};
      na.Ain = hE;
      na.W1 = Wtn1 + (size_t)l * 49152; na.koff1 = 256; na.ldw1 = 384;
      na.W2 = Wtn2 + (size_t)l * 16384; na.b2 = nb2c + l * 128;
      na.W3 = Wtn3 + (size_t)l * 16384; na.b3 = nb3c + l * 128;
      na.U = Ubuf; na.G = Gbuf; na.E = E_idx;
      na.out3 = t0;
      gc<0><<<RT / 128, 256, 0, stream>>>(na);
    }
    node_agg_ln_kernel<<<BN_, 128, 0, stream>>>(t0, ma, hV);
    {
      GCArgs nf{};
      nf.Ain = hV;
      nf.Wd1 = Wtnd1 + (size_t)l * 65536; nf.bd1 = nbd1c + l * 512;
      nf.Wd2 = Wtnd2 + (size_t)l * 65536; nf.bd2 = nbd2c + l * 128;
      nf.mvec = xmf; nf.outF = hV;
      gc<2><<<BN_ / 128, 256, 0, stream>>>(nf);
    }
    // ---- edge update (fully fused) ----
    g(dim3(1, BN_ / 128, 2), hV, 128, Wte1 + (size_t)l * 49152, 384, 0,
      eb1c + l * 128, 128, 128, EPI_F32,
      nullptr, Ubuf, Gbuf, 256, nullptr, NOM, 0);
    {
      GCArgs ea{};
      ea.Ain = hE;
      ea.W1 = Wte1 + (size_t)l * 49152; ea.koff1 = 128; ea.ldw1 = 384;
      ea.W2 = Wte2 + (size_t)l * 16384; ea.b2 = eb2c + l * 128;
      ea.W3 = Wte3 + (size_t)l * 16384; ea.b3 = eb3c + l * 128;
      ea.U = Ubuf; ea.G = Gbuf; ea.E = E_idx;
      ea.resid = hE;
      ea.Wd1 = Wted1 + (size_t)l * 65536; ea.bd1 = ebd1c + l * 512;
      ea.Wd2 = Wted2 + (size_t)l * 65536; ea.bd2 = ebd2c + l * 128;
      ea.mvec = ma; ea.outF = hE;
      gc<1><<<RT / 128, 256, 0, stream>>>(ea);
    }
  }

  // output head: fused merge_dups gather, dtype-aware store
  g(dim3(4, RT / 128), hE, 128, WtOut, 128, 0, outbc, ODIM_, 128, EPI_OUT,
    nullptr, nullptr, nullptr, 0, nullptr, NOM, 0);
}